// Round 9
// baseline (190.228 us; speedup 1.0000x reference)
//
#include <hip/hip_runtime.h>

#define HW 64
#define XR (66*64)       // staging region: 66 rows x 64 cols (rows 0,65 = zero pad)
#define LH 150
#define LQ 10

// weff[0..17] = sum_l r_w[l]*h_w[l][c][ky][kx], weff[18] = sum_l r_w[l]*h_b[l]
__global__ void vin_prep(const float* __restrict__ h_w,
                         const float* __restrict__ h_b,
                         const float* __restrict__ r_w,
                         float* __restrict__ weff) {
    int t = threadIdx.x;
    if (t < 18) {
        float s = 0.f;
        for (int l = 0; l < LH; ++l) s += r_w[l] * h_w[l*18 + t];
        weff[t] = s;
    } else if (t == 18) {
        float s = 0.f;
        for (int l = 0; l < LH; ++l) s += r_w[l] * h_b[l];
        weff[18] = s;
    }
}

// Full-wave lane shifts; bound_ctrl zero-fill == SAME padding at cols 0/63.
__device__ __forceinline__ float dpp_wshr1(float x) {   // lane i <- lane i-1
    return __builtin_bit_cast(float, __builtin_amdgcn_update_dpp(
        0, __builtin_bit_cast(int, x), 0x138, 0xF, 0xF, true));
}
__device__ __forceinline__ float dpp_wshl1(float x) {   // lane i <- lane i+1
    return __builtin_bit_cast(float, __builtin_amdgcn_update_dpp(
        0, __builtin_bit_cast(int, x), 0x130, 0xF, 0xF, true));
}

// One block per image, 512 threads = 8 waves. lane l = column l; wave w owns
// rows 8w..8w+7 in registers (scalar). Horizontal halos via wave DPP; vertical
// halos via 2 ds_write_b32 + 2 ds_read_b32 per lane per iter (parity slots).
// Inner loop is PURE SCALAR fp32: v_fma_f32 already runs at chip fp32 peak on
// CDNA4; f2 packed wrappers only added pack/unpack movs (R8 post-mortem).
__global__ __launch_bounds__(512, 2)
void vin_main(const float* __restrict__ X,
              const float* __restrict__ q_w,
              const float* __restrict__ wgt,
              const int* __restrict__ kptr,
              const float* __restrict__ ws,
              float* __restrict__ out) {
    __shared__ float smem[3*XR];           // 50688 B: X0 | X1 | r (halo slots alias X0)
    float* sR = smem + 2*XR;
    float* sHB = smem;                     // [2][9][64] bottom-row slots (pad [p][0]=0)
    float* sHT = smem + 1152;              // [2][9][64] top-row slots   (pad [p][8]=0)

    const int b = blockIdx.x, tid = threadIdx.x;
    const int w = tid >> 6, l = tid & 63;

    for (int i = tid; i < 3*XR; i += 512) smem[i] = 0.f;
    __syncthreads();

    // ---- stage X (both channels), image rows 0..63 -> LDS rows 1..64 ----
    const float* Xb = X + (size_t)b * 2 * HW * HW;
    for (int i = tid; i < 2*64*16; i += 512) {
        int ch = i >> 10, j = i & 1023, row = j >> 4, c = j & 15;
        float4 v = *(const float4*)(Xb + ((size_t)ch*HW + row)*HW + c*4);
        *(float4*)(smem + ch*XR + (row+1)*64 + c*4) = v;
    }
    __syncthreads();

    // ---- r = conv3x3(X, weff) + beff, column mapping ----
    float wE[19];
    #pragma unroll
    for (int i = 0; i < 19; ++i) wE[i] = ws[i];
    float rloc[8];
    {
        float xc[2][10], xl[2][10], xr[2][10];
        #pragma unroll
        for (int ch = 0; ch < 2; ++ch)
            #pragma unroll
            for (int k = 0; k < 10; ++k) {
                xc[ch][k] = smem[ch*XR + (8*w + k)*64 + l];   // global row 8w-1+k
                xl[ch][k] = dpp_wshr1(xc[ch][k]);
                xr[ch][k] = dpp_wshl1(xc[ch][k]);
            }
        #pragma unroll
        for (int i = 0; i < 8; ++i) {
            float acc = wE[18];
            #pragma unroll
            for (int ch = 0; ch < 2; ++ch)
                #pragma unroll
                for (int dy = 0; dy < 3; ++dy) {
                    acc = fmaf(xl[ch][i+dy], wE[ch*9 + dy*3 + 0], acc);
                    acc = fmaf(xc[ch][i+dy], wE[ch*9 + dy*3 + 1], acc);
                    acc = fmaf(xr[ch][i+dy], wE[ch*9 + dy*3 + 2], acc);
                }
            rloc[i] = acc;
        }
    }
    #pragma unroll
    for (int i = 0; i < 8; ++i) sR[(8*w + i + 1)*64 + l] = rloc[i];
    __syncthreads();   // X regions dead after this -> halo slots may alias

    // ---- qr[a][i] = conv3x3(r, q_w[a]); v0 = max_a qr ----
    float qr[LQ][8];
    float vc[8];
    {
        float rc[10], rl[10], rr2[10];
        #pragma unroll
        for (int k = 0; k < 10; ++k) {
            rc[k]  = sR[(8*w + k)*64 + l];
            rl[k]  = dpp_wshr1(rc[k]);
            rr2[k] = dpp_wshl1(rc[k]);
        }
        #pragma unroll
        for (int a = 0; a < LQ; ++a) {
            float qa[9];
            #pragma unroll
            for (int i = 0; i < 9; ++i) qa[i] = q_w[a*9 + i];
            #pragma unroll
            for (int i = 0; i < 8; ++i) {
                float s = 0.f;
                #pragma unroll
                for (int dy = 0; dy < 3; ++dy) {
                    s = fmaf(rl[i+dy],  qa[dy*3 + 0], s);
                    s = fmaf(rc[i+dy],  qa[dy*3 + 1], s);
                    s = fmaf(rr2[i+dy], qa[dy*3 + 2], s);
                }
                qr[a][i] = s;
                vc[i] = a ? fmaxf(vc[i], s) : s;
            }
        }
    }
    // zero the 4 halo pad rows (alias region; X dead since last barrier)
    if (tid < 256) {
        int p = tid >> 7, half = (tid >> 6) & 1, ll = tid & 63;
        if (half == 0) sHB[p*576 + 0*64 + ll] = 0.f;
        else           sHT[p*576 + 8*64 + ll] = 0.f;
    }

    float wv[LQ*9];
    #pragma unroll
    for (int i = 0; i < LQ*9; ++i) wv[i] = wgt[i];

    // ---- value iteration: v <- max_a (qr[a] + conv3x3(v, w[a])) ----
    const int km1 = kptr[0] - 1;
    const int wrB = (w+1)*64 + l;
    const int wrT = w*64 + l;
    for (int t = 0; t < km1; ++t) {
        const int p = (t & 1) * 576;
        sHB[p + wrB] = vc[7];       // my row 8w+7
        sHT[p + wrT] = vc[0];       // my row 8w
        __syncthreads();
        float ht = sHB[p + wrT];    // row 8w-1 (zero for w==0)
        float hb = sHT[p + wrB];    // row 8w+8 (zero for w==7)

        float vv[10], vl[10], vr[10];
        vv[0] = ht;
        #pragma unroll
        for (int i = 0; i < 8; ++i) vv[i+1] = vc[i];
        vv[9] = hb;
        #pragma unroll
        for (int k = 0; k < 10; ++k) { vl[k] = dpp_wshr1(vv[k]); vr[k] = dpp_wshl1(vv[k]); }

        #pragma unroll
        for (int i = 0; i < 8; ++i) {
            float acc[LQ];
            #pragma unroll
            for (int a = 0; a < LQ; ++a) {
                float s = qr[a][i];
                #pragma unroll
                for (int dy = 0; dy < 3; ++dy) {
                    s = fmaf(vl[i+dy], wv[a*9 + dy*3 + 0], s);
                    s = fmaf(vv[i+dy], wv[a*9 + dy*3 + 1], s);
                    s = fmaf(vr[i+dy], wv[a*9 + dy*3 + 2], s);
                }
                acc[a] = s;
            }
            // balanced max tree (v_max3-friendly)
            float t0 = fmaxf(fmaxf(acc[0], acc[1]), acc[2]);
            float t1 = fmaxf(fmaxf(acc[3], acc[4]), acc[5]);
            float t2 = fmaxf(fmaxf(acc[6], acc[7]), acc[8]);
            vc[i] = fmaxf(fmaxf(t0, t1), fmaxf(t2, acc[9]));
        }
    }

    // ---- write out: lane l -> column l, rows 8w..8w+7 ----
    float* ob = out + (size_t)b*HW*HW + (size_t)(8*w)*HW + l;
    #pragma unroll
    for (int i = 0; i < 8; ++i) ob[i*HW] = vc[i];
}

extern "C" void kernel_launch(void* const* d_in, const int* in_sizes, int n_in,
                              void* d_out, int out_size, void* d_ws, size_t ws_size,
                              hipStream_t stream) {
    const float* X   = (const float*)d_in[0];
    const float* h_w = (const float*)d_in[1];
    const float* h_b = (const float*)d_in[2];
    const float* r_w = (const float*)d_in[3];
    const float* q_w = (const float*)d_in[4];
    const float* w   = (const float*)d_in[5];
    const int*   k   = (const int*)d_in[6];
    float* out = (float*)d_out;
    float* ws  = (float*)d_ws;   // 19 floats

    vin_prep<<<1, 64, 0, stream>>>(h_w, h_b, r_w, ws);
    vin_main<<<128, 512, 0, stream>>>(X, q_w, w, k, ws, out);
}

// Round 10
// 152.031 us; speedup vs baseline: 1.2512x; 1.2512x over previous
//
#include <hip/hip_runtime.h>

typedef float f2 __attribute__((ext_vector_type(2)));

#define HW 64
#define XR (66*64)       // staging region: 66 rows x 64 cols (rows 0,65 = zero pad)
#define LH 150
#define LQ 10

// Full-wave lane shifts. wave_shr1 (0x138): lane i <- lane i-1 (lane 0 -> 0).
// wave_shl1 (0x130): lane i <- lane i+1 (lane 63 -> 0). bound_ctrl zero-fill
// == SAME padding at image columns 0 / 63 (lane == column).
__device__ __forceinline__ float dpp_wshr1(float x) {
    return __builtin_bit_cast(float, __builtin_amdgcn_update_dpp(
        0, __builtin_bit_cast(int, x), 0x138, 0xF, 0xF, true));
}
__device__ __forceinline__ float dpp_wshl1(float x) {
    return __builtin_bit_cast(float, __builtin_amdgcn_update_dpp(
        0, __builtin_bit_cast(int, x), 0x130, 0xF, 0xF, true));
}
__device__ __forceinline__ f2 dpp2_shr(f2 v) { return (f2){dpp_wshr1(v.x), dpp_wshr1(v.y)}; }
__device__ __forceinline__ f2 dpp2_shl(f2 v) { return (f2){dpp_wshl1(v.x), dpp_wshl1(v.y)}; }

// One block per image, 512 threads = 8 waves. lane l = column l; wave w owns
// rows 8w..8w+7 IN REGISTERS (f2 row-pairs). Horizontal halos via wave DPP;
// vertical halos via 2 ds_write_b32 + 2 ds_read_b32 per lane per iter.
// weff (fused h->r conv weights) computed in-block at prologue: the old
// separate 1-wave prep kernel was a ~45 us serial cold-load chain + launch.
__global__ __launch_bounds__(512, 2)
void vin_main(const float* __restrict__ X,
              const float* __restrict__ h_w,
              const float* __restrict__ h_b,
              const float* __restrict__ r_w,
              const float* __restrict__ q_w,
              const float* __restrict__ wgt,
              const int* __restrict__ kptr,
              float* __restrict__ out) {
    __shared__ float smem[3*XR + 32];      // X0 | X1 | r | weff stash (32)
    float* sR  = smem + 2*XR;
    float* sWE = smem + 3*XR;
    float* sHB = smem;                     // [2][9][64] bottom-row slots (pad [p][0]=0)
    float* sHT = smem + 1152;              // [2][9][64] top-row slots   (pad [p][8]=0)

    const int b = blockIdx.x, tid = threadIdx.x;
    const int w = tid >> 6, l = tid & 63;

    for (int i = tid; i < 3*XR + 32; i += 512) smem[i] = 0.f;
    __syncthreads();

    // ---- fused weff: wave w computes outputs j = w, w+8, w+16 (j<19) ----
    // weff[j<18] = sum_l r_w[l]*h_w[l*18+j]; weff[18] = sum_l r_w[l]*h_b[l]
    #pragma unroll
    for (int i = 0; i < 3; ++i) {
        int j = w + 8*i;
        if (j < 19) {
            float s = 0.f;
            #pragma unroll
            for (int u = 0; u < 3; ++u) {
                int t = l + 64*u;
                if (t < LH) {
                    float src = (j < 18) ? h_w[t*18 + j] : h_b[t];
                    s = fmaf(r_w[t], src, s);
                }
            }
            #pragma unroll
            for (int off = 32; off >= 1; off >>= 1)
                s += __shfl_xor(s, off);
            if (l == 0) sWE[j] = s;
        }
    }

    // ---- stage X (both channels), image rows 0..63 -> LDS rows 1..64 ----
    const float* Xb = X + (size_t)b * 2 * HW * HW;
    for (int i = tid; i < 2*64*16; i += 512) {
        int ch = i >> 10, j = i & 1023, row = j >> 4, c = j & 15;
        float4 v = *(const float4*)(Xb + ((size_t)ch*HW + row)*HW + c*4);
        *(float4*)(smem + ch*XR + (row+1)*64 + c*4) = v;
    }
    __syncthreads();

    // ---- r = conv3x3(X, weff) + beff, column mapping ----
    float wE[19];
    #pragma unroll
    for (int i = 0; i < 19; ++i) wE[i] = sWE[i];
    float rloc[8];
    {
        float xc[2][10], xl[2][10], xr[2][10];
        #pragma unroll
        for (int ch = 0; ch < 2; ++ch)
            #pragma unroll
            for (int k = 0; k < 10; ++k) {
                xc[ch][k] = smem[ch*XR + (8*w + k)*64 + l];   // global row 8w-1+k
                xl[ch][k] = dpp_wshr1(xc[ch][k]);
                xr[ch][k] = dpp_wshl1(xc[ch][k]);
            }
        #pragma unroll
        for (int i = 0; i < 8; ++i) {
            float acc = wE[18];
            #pragma unroll
            for (int ch = 0; ch < 2; ++ch)
                #pragma unroll
                for (int dy = 0; dy < 3; ++dy) {
                    acc = fmaf(xl[ch][i+dy], wE[ch*9 + dy*3 + 0], acc);
                    acc = fmaf(xc[ch][i+dy], wE[ch*9 + dy*3 + 1], acc);
                    acc = fmaf(xr[ch][i+dy], wE[ch*9 + dy*3 + 2], acc);
                }
            rloc[i] = acc;
        }
    }
    #pragma unroll
    for (int i = 0; i < 8; ++i) sR[(8*w + i + 1)*64 + l] = rloc[i];
    __syncthreads();   // X regions dead after this -> halo slots may alias

    // ---- qr[a] = conv3x3(r, q_w[a]); v0 = max_a qr ----
    f2 qr[LQ][4];
    f2 vc[4];
    {
        float rc[10], rl[10], rr2[10];
        #pragma unroll
        for (int k = 0; k < 10; ++k) {
            rc[k]  = sR[(8*w + k)*64 + l];
            rl[k]  = dpp_wshr1(rc[k]);
            rr2[k] = dpp_wshl1(rc[k]);
        }
        float vcur[8];
        #pragma unroll
        for (int a = 0; a < LQ; ++a) {
            float qa[9];
            #pragma unroll
            for (int i = 0; i < 9; ++i) qa[i] = q_w[a*9 + i];
            float acc[8];
            #pragma unroll
            for (int i = 0; i < 8; ++i) {
                float s = 0.f;
                #pragma unroll
                for (int dy = 0; dy < 3; ++dy) {
                    s = fmaf(rl[i+dy],  qa[dy*3 + 0], s);
                    s = fmaf(rc[i+dy],  qa[dy*3 + 1], s);
                    s = fmaf(rr2[i+dy], qa[dy*3 + 2], s);
                }
                acc[i] = s;
                vcur[i] = a ? fmaxf(vcur[i], s) : s;
            }
            #pragma unroll
            for (int j = 0; j < 4; ++j) qr[a][j] = (f2){acc[2*j], acc[2*j+1]};
        }
        #pragma unroll
        for (int j = 0; j < 4; ++j) vc[j] = (f2){vcur[2*j], vcur[2*j+1]};
    }
    // zero the 4 halo pad rows (alias region; X dead since last barrier)
    if (tid < 256) {
        int p = tid >> 7, half = (tid >> 6) & 1, ll = tid & 63;
        if (half == 0) sHB[p*576 + 0*64 + ll] = 0.f;
        else           sHT[p*576 + 8*64 + ll] = 0.f;
    }

    float wv[LQ*9];
    #pragma unroll
    for (int i = 0; i < LQ*9; ++i) wv[i] = wgt[i];

    // ---- value iteration: v <- max_a (qr[a] + conv3x3(v, w[a])) ----
    const int km1 = kptr[0] - 1;
    const int wrB = (w+1)*64 + l;   // my bottom-row slot / partner's top-halo index
    const int wrT = w*64 + l;
    for (int t = 0; t < km1; ++t) {
        const int p = (t & 1) * 576;
        sHB[p + wrB] = vc[3].y;     // my row 8w+7
        sHT[p + wrT] = vc[0].x;     // my row 8w
        __syncthreads();
        float ht = sHB[p + wrT];    // row 8w-1 (zero for w==0)
        float hb = sHT[p + wrB];    // row 8w+8 (zero for w==7)

        // vv[0..9] = [ht, vcur0..7, hb]; aligned pairs P[j], odd pairs = vc[j]
        f2 P[5];
        P[0] = (f2){ht,       vc[0].x};
        P[1] = (f2){vc[0].y,  vc[1].x};
        P[2] = (f2){vc[1].y,  vc[2].x};
        P[3] = (f2){vc[2].y,  vc[3].x};
        P[4] = (f2){vc[3].y,  hb};
        f2 PL[5], PR[5], OL[4], OR[4];
        #pragma unroll
        for (int j = 0; j < 5; ++j) { PL[j] = dpp2_shr(P[j]); PR[j] = dpp2_shl(P[j]); }
        #pragma unroll
        for (int j = 0; j < 4; ++j) { OL[j] = dpp2_shr(vc[j]); OR[j] = dpp2_shl(vc[j]); }

        f2 vn[4];
        #pragma unroll
        for (int a = 0; a < LQ; ++a) {
            f2 acc[4];
            #pragma unroll
            for (int j = 0; j < 4; ++j) acc[j] = qr[a][j];
            #pragma unroll
            for (int j = 0; j < 4; ++j) {
                float w00 = wv[a*9+0], w01 = wv[a*9+1], w02 = wv[a*9+2];
                float w10 = wv[a*9+3], w11 = wv[a*9+4], w12 = wv[a*9+5];
                float w20 = wv[a*9+6], w21 = wv[a*9+7], w22 = wv[a*9+8];
                acc[j] = __builtin_elementwise_fma(PL[j],   (f2){w00,w00}, acc[j]);
                acc[j] = __builtin_elementwise_fma(P[j],    (f2){w01,w01}, acc[j]);
                acc[j] = __builtin_elementwise_fma(PR[j],   (f2){w02,w02}, acc[j]);
                acc[j] = __builtin_elementwise_fma(OL[j],   (f2){w10,w10}, acc[j]);
                acc[j] = __builtin_elementwise_fma(vc[j],   (f2){w11,w11}, acc[j]);
                acc[j] = __builtin_elementwise_fma(OR[j],   (f2){w12,w12}, acc[j]);
                acc[j] = __builtin_elementwise_fma(PL[j+1], (f2){w20,w20}, acc[j]);
                acc[j] = __builtin_elementwise_fma(P[j+1],  (f2){w21,w21}, acc[j]);
                acc[j] = __builtin_elementwise_fma(PR[j+1], (f2){w22,w22}, acc[j]);
            }
            if (a == 0) { vn[0]=acc[0]; vn[1]=acc[1]; vn[2]=acc[2]; vn[3]=acc[3]; }
            else {
                vn[0] = __builtin_elementwise_max(vn[0], acc[0]);
                vn[1] = __builtin_elementwise_max(vn[1], acc[1]);
                vn[2] = __builtin_elementwise_max(vn[2], acc[2]);
                vn[3] = __builtin_elementwise_max(vn[3], acc[3]);
            }
        }
        vc[0] = vn[0]; vc[1] = vn[1]; vc[2] = vn[2]; vc[3] = vn[3];
    }

    // ---- write out: lane l -> column l, rows 8w..8w+7 (coalesced per wave) ----
    float* ob = out + (size_t)b*HW*HW + (size_t)(8*w)*HW + l;
    #pragma unroll
    for (int j = 0; j < 4; ++j) {
        ob[(2*j)*HW]   = vc[j].x;
        ob[(2*j+1)*HW] = vc[j].y;
    }
}

extern "C" void kernel_launch(void* const* d_in, const int* in_sizes, int n_in,
                              void* d_out, int out_size, void* d_ws, size_t ws_size,
                              hipStream_t stream) {
    const float* X   = (const float*)d_in[0];
    const float* h_w = (const float*)d_in[1];
    const float* h_b = (const float*)d_in[2];
    const float* r_w = (const float*)d_in[3];
    const float* q_w = (const float*)d_in[4];
    const float* w   = (const float*)d_in[5];
    const int*   k   = (const int*)d_in[6];
    float* out = (float*)d_out;

    vin_main<<<128, 512, 0, stream>>>(X, h_w, h_b, r_w, q_w, w, k, out);
}

// Round 12
// 150.365 us; speedup vs baseline: 1.2651x; 1.0111x over previous
//
#include <hip/hip_runtime.h>

typedef float f2 __attribute__((ext_vector_type(2)));

#define HW 64
#define XR (66*64)       // staging region: 66 rows x 64 cols (rows 0,65 = zero pad)
#define LH 150
#define LQ 10

// Full-wave lane shifts; bound_ctrl zero-fill == SAME padding at cols 0/63.
__device__ __forceinline__ float dpp_wshr1(float x) {   // lane i <- lane i-1
    return __builtin_bit_cast(float, __builtin_amdgcn_update_dpp(
        0, __builtin_bit_cast(int, x), 0x138, 0xF, 0xF, true));
}
__device__ __forceinline__ float dpp_wshl1(float x) {   // lane i <- lane i+1
    return __builtin_bit_cast(float, __builtin_amdgcn_update_dpp(
        0, __builtin_bit_cast(int, x), 0x130, 0xF, 0xF, true));
}
__device__ __forceinline__ f2 dpp2_shr(f2 v) { return (f2){dpp_wshr1(v.x), dpp_wshr1(v.y)}; }
__device__ __forceinline__ f2 dpp2_shl(f2 v) { return (f2){dpp_wshl1(v.x), dpp_wshl1(v.y)}; }

// VOP3P packed fp32 FMA with weight broadcast from one word of a pair.
// b0: both halves use word0 of wpair; b1: both halves use word1.
// (v_pk_max_f32 does NOT exist on gfx950 — max is done with scalar v_max_f32.)
__device__ __forceinline__ f2 pk_fma_b0(f2 a, f2 wpair, f2 c) {
    f2 d;
    asm("v_pk_fma_f32 %0, %1, %2, %3 op_sel_hi:[1,0,1]"
        : "=v"(d) : "v"(a), "v"(wpair), "v"(c));
    return d;
}
__device__ __forceinline__ f2 pk_fma_b1(f2 a, f2 wpair, f2 c) {
    f2 d;
    asm("v_pk_fma_f32 %0, %1, %2, %3 op_sel:[0,1,0]"
        : "=v"(d) : "v"(a), "v"(wpair), "v"(c));
    return d;
}

// One block per image, 512 threads = 8 waves. lane l = column l; wave w owns
// rows 8w..8w+7 in registers (f2 row-pairs). Horizontal halos via wave DPP;
// vertical halos via 2 ds_write_b32 + 2 ds_read_b32 per lane per iter.
// Inner loop hand-packed with v_pk_fma_f32 (compiler lowers f2 elementwise
// builtins to scalar v_fma — R10 post-mortem issue-count audit).
__global__ __launch_bounds__(512, 2)
void vin_main(const float* __restrict__ X,
              const float* __restrict__ h_w,
              const float* __restrict__ h_b,
              const float* __restrict__ r_w,
              const float* __restrict__ q_w,
              const float* __restrict__ wgt,
              const int* __restrict__ kptr,
              float* __restrict__ out) {
    __shared__ float smem[3*XR + 32];      // X0 | X1 | r | weff stash (32)
    float* sR  = smem + 2*XR;
    float* sWE = smem + 3*XR;
    float* sHB = smem;                     // [2][9][64] bottom-row slots (pad [p][0]=0)
    float* sHT = smem + 1152;              // [2][9][64] top-row slots   (pad [p][8]=0)

    const int b = blockIdx.x, tid = threadIdx.x;
    const int w = tid >> 6, l = tid & 63;

    for (int i = tid; i < 3*XR + 32; i += 512) smem[i] = 0.f;
    __syncthreads();

    // ---- fused weff: wave w computes outputs j = w, w+8, w+16 (j<19) ----
    #pragma unroll
    for (int i = 0; i < 3; ++i) {
        int j = w + 8*i;
        if (j < 19) {
            float s = 0.f;
            #pragma unroll
            for (int u = 0; u < 3; ++u) {
                int t = l + 64*u;
                if (t < LH) {
                    float src = (j < 18) ? h_w[t*18 + j] : h_b[t];
                    s = fmaf(r_w[t], src, s);
                }
            }
            #pragma unroll
            for (int off = 32; off >= 1; off >>= 1)
                s += __shfl_xor(s, off);
            if (l == 0) sWE[j] = s;
        }
    }

    // ---- stage X (both channels), image rows 0..63 -> LDS rows 1..64 ----
    const float* Xb = X + (size_t)b * 2 * HW * HW;
    for (int i = tid; i < 2*64*16; i += 512) {
        int ch = i >> 10, j = i & 1023, row = j >> 4, c = j & 15;
        float4 v = *(const float4*)(Xb + ((size_t)ch*HW + row)*HW + c*4);
        *(float4*)(smem + ch*XR + (row+1)*64 + c*4) = v;
    }
    __syncthreads();

    // ---- r = conv3x3(X, weff) + beff, column mapping ----
    float wE[19];
    #pragma unroll
    for (int i = 0; i < 19; ++i) wE[i] = sWE[i];
    float rloc[8];
    {
        float xc[2][10], xl[2][10], xr[2][10];
        #pragma unroll
        for (int ch = 0; ch < 2; ++ch)
            #pragma unroll
            for (int k = 0; k < 10; ++k) {
                xc[ch][k] = smem[ch*XR + (8*w + k)*64 + l];   // global row 8w-1+k
                xl[ch][k] = dpp_wshr1(xc[ch][k]);
                xr[ch][k] = dpp_wshl1(xc[ch][k]);
            }
        #pragma unroll
        for (int i = 0; i < 8; ++i) {
            float acc = wE[18];
            #pragma unroll
            for (int ch = 0; ch < 2; ++ch)
                #pragma unroll
                for (int dy = 0; dy < 3; ++dy) {
                    acc = fmaf(xl[ch][i+dy], wE[ch*9 + dy*3 + 0], acc);
                    acc = fmaf(xc[ch][i+dy], wE[ch*9 + dy*3 + 1], acc);
                    acc = fmaf(xr[ch][i+dy], wE[ch*9 + dy*3 + 2], acc);
                }
            rloc[i] = acc;
        }
    }
    #pragma unroll
    for (int i = 0; i < 8; ++i) sR[(8*w + i + 1)*64 + l] = rloc[i];
    __syncthreads();   // X regions dead after this -> halo slots may alias

    // ---- qr[a] = conv3x3(r, q_w[a]); v0 = max_a qr ----
    f2 qr[LQ][4];
    f2 vc[4];
    {
        float rc[10], rl[10], rr2[10];
        #pragma unroll
        for (int k = 0; k < 10; ++k) {
            rc[k]  = sR[(8*w + k)*64 + l];
            rl[k]  = dpp_wshr1(rc[k]);
            rr2[k] = dpp_wshl1(rc[k]);
        }
        float vcur[8];
        #pragma unroll
        for (int a = 0; a < LQ; ++a) {
            float qa[9];
            #pragma unroll
            for (int i = 0; i < 9; ++i) qa[i] = q_w[a*9 + i];
            float acc[8];
            #pragma unroll
            for (int i = 0; i < 8; ++i) {
                float s = 0.f;
                #pragma unroll
                for (int dy = 0; dy < 3; ++dy) {
                    s = fmaf(rl[i+dy],  qa[dy*3 + 0], s);
                    s = fmaf(rc[i+dy],  qa[dy*3 + 1], s);
                    s = fmaf(rr2[i+dy], qa[dy*3 + 2], s);
                }
                acc[i] = s;
                vcur[i] = a ? fmaxf(vcur[i], s) : s;
            }
            #pragma unroll
            for (int j = 0; j < 4; ++j) qr[a][j] = (f2){acc[2*j], acc[2*j+1]};
        }
        #pragma unroll
        for (int j = 0; j < 4; ++j) vc[j] = (f2){vcur[2*j], vcur[2*j+1]};
    }
    // zero the 4 halo pad rows (alias region; X dead since last barrier)
    if (tid < 256) {
        int p = tid >> 7, half = (tid >> 6) & 1, ll = tid & 63;
        if (half == 0) sHB[p*576 + 0*64 + ll] = 0.f;
        else           sHT[p*576 + 8*64 + ll] = 0.f;
    }

    // ---- weights as 45 packed pairs: wv2[a][p] = (wgt[a*9+2p], wgt[a*9+2p+1]) ----
    f2 wv2[LQ][5];
    #pragma unroll
    for (int a = 0; a < LQ; ++a) {
        #pragma unroll
        for (int p = 0; p < 4; ++p)
            wv2[a][p] = (f2){wgt[a*9 + 2*p], wgt[a*9 + 2*p + 1]};
        wv2[a][4] = (f2){wgt[a*9 + 8], 0.f};
    }

    // ---- value iteration: v <- max_a (qr[a] + conv3x3(v, w[a])) ----
    const int km1 = kptr[0] - 1;
    const int wrB = (w+1)*64 + l;   // my bottom-row slot / partner's top-halo index
    const int wrT = w*64 + l;
    for (int t = 0; t < km1; ++t) {
        const int p = (t & 1) * 576;
        sHB[p + wrB] = vc[3].y;     // my row 8w+7
        sHT[p + wrT] = vc[0].x;     // my row 8w
        __syncthreads();
        float ht = sHB[p + wrT];    // row 8w-1 (zero for w==0)
        float hb = sHT[p + wrB];    // row 8w+8 (zero for w==7)

        // vv[0..9] = [ht, v0..v7, hb]; aligned pairs P[j]; odd pairs = vc[j]
        f2 P[5];
        P[0] = (f2){ht,       vc[0].x};
        P[1] = (f2){vc[0].y,  vc[1].x};
        P[2] = (f2){vc[1].y,  vc[2].x};
        P[3] = (f2){vc[2].y,  vc[3].x};
        P[4] = (f2){vc[3].y,  hb};
        f2 PL[5], PR[5], OL[4], OR[4];
        #pragma unroll
        for (int j = 0; j < 5; ++j) { PL[j] = dpp2_shr(P[j]); PR[j] = dpp2_shl(P[j]); }
        #pragma unroll
        for (int j = 0; j < 4; ++j) { OL[j] = dpp2_shr(vc[j]); OR[j] = dpp2_shl(vc[j]); }

        f2 vn[4];
        #pragma unroll
        for (int a = 0; a < LQ; ++a) {
            #pragma unroll
            for (int j = 0; j < 4; ++j) {
                // taps: dy=0 -> P[j], dy=1 -> vc[j] (odd), dy=2 -> P[j+1]; cols L/C/R
                f2 acc = qr[a][j];
                acc = pk_fma_b0(PL[j],   wv2[a][0], acc);  // w0
                acc = pk_fma_b1(P[j],    wv2[a][0], acc);  // w1
                acc = pk_fma_b0(PR[j],   wv2[a][1], acc);  // w2
                acc = pk_fma_b1(OL[j],   wv2[a][1], acc);  // w3
                acc = pk_fma_b0(vc[j],   wv2[a][2], acc);  // w4
                acc = pk_fma_b1(OR[j],   wv2[a][2], acc);  // w5
                acc = pk_fma_b0(PL[j+1], wv2[a][3], acc);  // w6
                acc = pk_fma_b1(P[j+1],  wv2[a][3], acc);  // w7
                acc = pk_fma_b0(PR[j+1], wv2[a][4], acc);  // w8
                vn[j] = (a == 0) ? acc : __builtin_elementwise_max(vn[j], acc);
            }
        }
        vc[0] = vn[0]; vc[1] = vn[1]; vc[2] = vn[2]; vc[3] = vn[3];
    }

    // ---- write out: lane l -> column l, rows 8w..8w+7 (coalesced per wave) ----
    float* ob = out + (size_t)b*HW*HW + (size_t)(8*w)*HW + l;
    #pragma unroll
    for (int j = 0; j < 4; ++j) {
        ob[(2*j)*HW]   = vc[j].x;
        ob[(2*j+1)*HW] = vc[j].y;
    }
}

extern "C" void kernel_launch(void* const* d_in, const int* in_sizes, int n_in,
                              void* d_out, int out_size, void* d_ws, size_t ws_size,
                              hipStream_t stream) {
    const float* X   = (const float*)d_in[0];
    const float* h_w = (const float*)d_in[1];
    const float* h_b = (const float*)d_in[2];
    const float* r_w = (const float*)d_in[3];
    const float* q_w = (const float*)d_in[4];
    const float* w   = (const float*)d_in[5];
    const int*   k   = (const int*)d_in[6];
    float* out = (float*)d_out;

    vin_main<<<128, 512, 0, stream>>>(X, h_w, h_b, r_w, q_w, w, k, out);
}